// Round 1
// baseline (489.668 us; speedup 1.0000x reference)
//
#include <hip/hip_runtime.h>
#include <hip/hip_bf16.h>

typedef __hip_bfloat16 bf16_t;
typedef __bf16 bf16x8 __attribute__((ext_vector_type(8)));
typedef float f32x4 __attribute__((ext_vector_type(4)));

__device__ __forceinline__ void gload_lds16(const void* g, void* l) {
  __builtin_amdgcn_global_load_lds(
      (const __attribute__((address_space(1))) void*)g,
      (__attribute__((address_space(3))) void*)l, 16, 0, 0);
}

__device__ __forceinline__ unsigned short f2bf(float f) {
  bf16_t h = __float2bfloat16(f);
  return reinterpret_cast<unsigned short&>(h);
}

// ---------------- weight transpose: fp32 [K][N] -> bf16 [N][K] ----------------
__global__ __launch_bounds__(256) void wtrans_kernel(
    const float* __restrict__ in, bf16_t* __restrict__ out, int K, int N) {
  __shared__ float tile[32][33];
  int tx = threadIdx.x, ty = threadIdx.y;
  int n = blockIdx.x * 32 + tx;
  int k0 = blockIdx.y * 32 + ty;
#pragma unroll
  for (int j = 0; j < 32; j += 8) tile[ty + j][tx] = in[(size_t)(k0 + j) * N + n];
  __syncthreads();
  int k = blockIdx.y * 32 + tx;
  int n0 = blockIdx.x * 32 + ty;
#pragma unroll
  for (int j = 0; j < 32; j += 8)
    out[(size_t)(n0 + j) * K + k] = __float2bfloat16(tile[tx][ty + j]);
}

// ---------------- LayerNorm (+ optional pos_emb) -> bf16 ----------------
// one block per row, 256 threads, D=1024
__global__ __launch_bounds__(256) void ln_kernel(
    const float* __restrict__ x, const float* __restrict__ g,
    const float* __restrict__ b, const float* __restrict__ pos,
    bf16_t* __restrict__ out, int S) {
  int row = blockIdx.x;
  int tid = threadIdx.x;
  const float4* xr = (const float4*)(x + (size_t)row * 1024);
  float4 v = xr[tid];
  float s1 = v.x + v.y + v.z + v.w;
  float s2 = v.x * v.x + v.y * v.y + v.z * v.z + v.w * v.w;
#pragma unroll
  for (int off = 1; off < 64; off <<= 1) {
    s1 += __shfl_xor(s1, off);
    s2 += __shfl_xor(s2, off);
  }
  __shared__ float red[2][4];
  int w = tid >> 6;
  if ((tid & 63) == 0) { red[0][w] = s1; red[1][w] = s2; }
  __syncthreads();
  s1 = red[0][0] + red[0][1] + red[0][2] + red[0][3];
  s2 = red[1][0] + red[1][1] + red[1][2] + red[1][3];
  float mu = s1 * (1.f / 1024.f);
  float var = s2 * (1.f / 1024.f) - mu * mu;
  float rs = rsqrtf(var + 1e-5f);
  float4 gg = ((const float4*)g)[tid];
  float4 bb = ((const float4*)b)[tid];
  float4 pp = {0.f, 0.f, 0.f, 0.f};
  if (pos) pp = ((const float4*)(pos + (size_t)(row & (S - 1)) * 1024))[tid];
  ushort4 o4;
  o4.x = f2bf((v.x - mu) * rs * gg.x + bb.x + pp.x);
  o4.y = f2bf((v.y - mu) * rs * gg.y + bb.y + pp.y);
  o4.z = f2bf((v.z - mu) * rs * gg.z + bb.z + pp.z);
  o4.w = f2bf((v.w - mu) * rs * gg.w + bb.w + pp.w);
  ((ushort4*)(out + (size_t)row * 1024))[tid] = o4;
}

// ---------------- GEMM: C[M,N] = A[M,K](bf16) * BT[N,K]^T(bf16) + bias ----------------
// 128x128 tile, BK=64, 256 threads (4 waves, 2x2), mfma 16x16x32 bf16.
// LDS tiles XOR-swizzled: byte ^= ((row&7)<<4); staged via global_load_lds with
// pre-swizzled global source (linear LDS dest).
// EPI: 0 = QKV scatter (q/k [BH,S,64], v transposed [BH,64,S])
//      1 = out_f32 = resid + acc + bias
//      2 = out_bf16 = gelu_tanh(acc + bias)
template <int EPI>
__global__ __launch_bounds__(256) void gemm_bt(
    const bf16_t* __restrict__ A, const bf16_t* __restrict__ BT,
    const float* __restrict__ bias, const float* __restrict__ resid,
    float* __restrict__ outf, bf16_t* __restrict__ outb,
    bf16_t* __restrict__ qb, bf16_t* __restrict__ kb, bf16_t* __restrict__ vb,
    int M, int N, int K) {
  __shared__ char lds[32768];
  char* As = lds;
  char* Bs = lds + 16384;
  int tid = threadIdx.x;
  int l = tid & 63;
  int w = tid >> 6;
  int wr = w >> 1, wc = w & 1;
  int ll = l & 15, lg = l >> 4;
  int rowBase = blockIdx.y * 128, colBase = blockIdx.x * 128;

  f32x4 acc[4][4];
  f32x4 z = {0.f, 0.f, 0.f, 0.f};
#pragma unroll
  for (int i = 0; i < 4; i++)
#pragma unroll
    for (int j = 0; j < 4; j++) acc[i][j] = z;

  int nkt = K >> 6;
  for (int kt = 0; kt < nkt; ++kt) {
    __syncthreads();
#pragma unroll
    for (int i = 0; i < 4; i++) {
      int p = i * 4096 + tid * 16;
      int o = p ^ (((p >> 7) & 7) << 4);
      int r = o >> 7, c = (o & 127) >> 1;
      gload_lds16(A + (size_t)(rowBase + r) * K + kt * 64 + c, As + p);
    }
#pragma unroll
    for (int i = 0; i < 4; i++) {
      int p = i * 4096 + tid * 16;
      int o = p ^ (((p >> 7) & 7) << 4);
      int r = o >> 7, c = (o & 127) >> 1;
      gload_lds16(BT + (size_t)(colBase + r) * K + kt * 64 + c, Bs + p);
    }
    __syncthreads();

    bf16x8 af[4][2], bfv[4][2];
#pragma unroll
    for (int mi = 0; mi < 4; mi++) {
      int row = wr * 64 + mi * 16 + ll;
#pragma unroll
      for (int kk = 0; kk < 2; kk++) {
        int o = (row << 7) + (kk << 6) + (lg << 4);
        af[mi][kk] = *(const bf16x8*)(As + (o ^ ((row & 7) << 4)));
      }
    }
#pragma unroll
    for (int ni = 0; ni < 4; ni++) {
      int row = wc * 64 + ni * 16 + ll;
#pragma unroll
      for (int kk = 0; kk < 2; kk++) {
        int o = (row << 7) + (kk << 6) + (lg << 4);
        bfv[ni][kk] = *(const bf16x8*)(Bs + (o ^ ((row & 7) << 4)));
      }
    }
#pragma unroll
    for (int mi = 0; mi < 4; mi++)
#pragma unroll
      for (int ni = 0; ni < 4; ni++)
#pragma unroll
        for (int kk = 0; kk < 2; kk++)
          acc[mi][ni] = __builtin_amdgcn_mfma_f32_16x16x32_bf16(
              af[mi][kk], bfv[ni][kk], acc[mi][ni], 0, 0, 0);
  }

  // epilogue
#pragma unroll
  for (int mi = 0; mi < 4; mi++) {
#pragma unroll
    for (int ni = 0; ni < 4; ni++) {
#pragma unroll
      for (int j = 0; j < 4; j++) {
        int grow = rowBase + wr * 64 + mi * 16 + lg * 4 + j;
        int gcol = colBase + wc * 64 + ni * 16 + ll;
        float v = acc[mi][ni][j] + bias[gcol];
        if (EPI == 0) {
          int bb = grow >> 11, s = grow & 2047;
          int t = gcol >> 10, rem = gcol & 1023;
          int h = rem >> 6, d = rem & 63;
          size_t bh = (size_t)(bb * 16 + h);
          if (t == 0)
            qb[(bh * 2048 + s) * 64 + d] = __float2bfloat16(v);
          else if (t == 1)
            kb[(bh * 2048 + s) * 64 + d] = __float2bfloat16(v);
          else
            vb[(bh * 64 + d) * 2048 + s] = __float2bfloat16(v);
        } else if (EPI == 1) {
          size_t idx = (size_t)grow * N + gcol;
          outf[idx] = resid[idx] + v;
        } else {
          float c3 = v * v * v;
          float t = tanhf(0.7978845608028654f * (v + 0.044715f * c3));
          outb[(size_t)grow * N + gcol] = __float2bfloat16(0.5f * v * (1.f + t));
        }
      }
    }
  }
}

// ---------------- flash attention (causal), HD=64 ----------------
// grid (S/64, B*H), 256 threads (4 waves, 16 q-rows each).
// q,k: [BH][S][64] bf16 ; vT: [BH][64][S] bf16 ; out: [B,S,1024] bf16
__global__ __launch_bounds__(256) void attn_kernel(
    const bf16_t* __restrict__ qb, const bf16_t* __restrict__ kb,
    const bf16_t* __restrict__ vbT, bf16_t* __restrict__ op, int S) {
  int qt = blockIdx.x;
  int bh = blockIdx.y;
  int tid = threadIdx.x;
  int w = tid >> 6, l = tid & 63;
  int ll = l & 15, lg = l >> 4;
  __shared__ char lds[24576];
  char* Kt = lds;            // 64x64 bf16, swizzled
  char* Vt = lds + 8192;     // 64(d) x 64(s) bf16, swizzled
  char* Pw = lds + 16384 + w * 2048;  // per-wave 16x64 bf16 P tile, swizzled

  int qbase = qt * 64;
  int qrow = qbase + w * 16 + ll;
  const bf16_t* qrp = qb + ((size_t)bh * S + qrow) * 64;
  bf16x8 qf[2];
  qf[0] = *(const bf16x8*)(qrp + lg * 8);
  qf[1] = *(const bf16x8*)(qrp + 32 + lg * 8);

  f32x4 Oacc[4];
  f32x4 z = {0.f, 0.f, 0.f, 0.f};
#pragma unroll
  for (int i = 0; i < 4; i++) Oacc[i] = z;
  float mrow[4], lrow[4];
#pragma unroll
  for (int j = 0; j < 4; j++) { mrow[j] = -INFINITY; lrow[j] = 0.f; }

  for (int kt = 0; kt <= qt; ++kt) {
    __syncthreads();  // previous iteration's LDS reads done
#pragma unroll
    for (int i = 0; i < 2; ++i) {  // stage K tile (8KB)
      int p = i * 4096 + tid * 16;
      int o = p ^ (((p >> 7) & 7) << 4);
      int r = o >> 7, c = (o & 127) >> 1;
      gload_lds16(kb + ((size_t)bh * S + kt * 64 + r) * 64 + c, Kt + p);
    }
#pragma unroll
    for (int i = 0; i < 2; ++i) {  // stage V^T tile (8KB)
      int p = i * 4096 + tid * 16;
      int o = p ^ (((p >> 7) & 7) << 4);
      int d = o >> 7, c = (o & 127) >> 1;
      gload_lds16(vbT + ((size_t)bh * 64 + d) * S + kt * 64 + c, Vt + p);
    }
    __syncthreads();  // staging complete (vmcnt drained before barrier)

    // S = Q K^T
    f32x4 sfr[4];
#pragma unroll
    for (int f = 0; f < 4; f++) {
      sfr[f] = z;
#pragma unroll
      for (int kk = 0; kk < 2; kk++) {
        int row = f * 16 + ll;
        int o = (row << 7) + (kk << 6) + (lg << 4);
        bf16x8 kf = *(const bf16x8*)(Kt + (o ^ ((row & 7) << 4)));
        sfr[f] = __builtin_amdgcn_mfma_f32_16x16x32_bf16(qf[kk], kf, sfr[f], 0, 0, 0);
      }
    }
    // online softmax (rows spread: row = lg*4+j across 16 lanes ll)
#pragma unroll
    for (int j = 0; j < 4; j++) {
      int qr = w * 16 + lg * 4 + j;  // local q row in tile
      float mx = -INFINITY;
#pragma unroll
      for (int f = 0; f < 4; f++) {
        float s = sfr[f][j] * 0.125f;
        if (kt == qt && (kt * 64 + f * 16 + ll) > (qbase + qr)) s = -INFINITY;
        sfr[f][j] = s;
        mx = fmaxf(mx, s);
      }
#pragma unroll
      for (int off = 1; off < 16; off <<= 1) mx = fmaxf(mx, __shfl_xor(mx, off));
      float mnew = fmaxf(mrow[j], mx);
      float fj = __expf(mrow[j] - mnew);
      float sum = 0.f;
#pragma unroll
      for (int f = 0; f < 4; f++) {
        float p = __expf(sfr[f][j] - mnew);
        sfr[f][j] = p;
        sum += p;
      }
#pragma unroll
      for (int off = 1; off < 16; off <<= 1) sum += __shfl_xor(sum, off);
      lrow[j] = lrow[j] * fj + sum;
      mrow[j] = mnew;
#pragma unroll
      for (int fd = 0; fd < 4; fd++) Oacc[fd][j] *= fj;
    }
    // write P (bf16) to per-wave LDS tile, swizzled
#pragma unroll
    for (int j = 0; j < 4; j++) {
      int r = lg * 4 + j;
#pragma unroll
      for (int f = 0; f < 4; f++) {
        int o = (r << 7) + ((f * 16 + ll) << 1);
        *(unsigned short*)(Pw + (o ^ ((r & 7) << 4))) = f2bf(sfr[f][j]);
      }
    }
    __syncthreads();  // P visible (and K-tile reads drained)

    // O += P V
#pragma unroll
    for (int kk = 0; kk < 2; kk++) {
      int pr = ll;
      int o = (pr << 7) + (kk << 6) + (lg << 4);
      bf16x8 pf = *(const bf16x8*)(Pw + (o ^ ((pr & 7) << 4)));
#pragma unroll
      for (int fd = 0; fd < 4; fd++) {
        int d = fd * 16 + ll;
        int o2 = (d << 7) + (kk << 6) + (lg << 4);
        bf16x8 vf = *(const bf16x8*)(Vt + (o2 ^ ((d & 7) << 4)));
        Oacc[fd] = __builtin_amdgcn_mfma_f32_16x16x32_bf16(pf, vf, Oacc[fd], 0, 0, 0);
      }
    }
  }

  int b = bh >> 4, hh = bh & 15;
#pragma unroll
  for (int j = 0; j < 4; j++) {
    int srow = qbase + (w << 4) + (lg << 2) + j;
    float inv = 1.f / lrow[j];
#pragma unroll
    for (int fd = 0; fd < 4; fd++) {
      int col = (hh << 6) + (fd << 4) + ll;
      op[((size_t)b * S + srow) * 1024 + col] = __float2bfloat16(Oacc[fd][j] * inv);
    }
  }
}

// ---------------- launch ----------------
extern "C" void kernel_launch(void* const* d_in, const int* in_sizes, int n_in,
                              void* d_out, int out_size, void* d_ws, size_t ws_size,
                              hipStream_t stream) {
  const float* x = (const float*)d_in[0];
  const float* pos_emb = (const float*)d_in[1];
  const float* ln1_g = (const float*)d_in[2];
  const float* ln1_b = (const float*)d_in[3];
  const float* w_qkv = (const float*)d_in[4];
  const float* b_qkv = (const float*)d_in[5];
  const float* w_o = (const float*)d_in[6];
  const float* b_o = (const float*)d_in[7];
  const float* ln2_g = (const float*)d_in[8];
  const float* ln2_b = (const float*)d_in[9];
  const float* w_fc = (const float*)d_in[10];
  const float* b_fc = (const float*)d_in[11];
  const float* w_proj = (const float*)d_in[12];
  const float* b_proj = (const float*)d_in[13];

  char* ws = (char*)d_ws;
  auto take = [&](size_t bytes) {
    char* p = ws;
    ws += (bytes + 255) & ~(size_t)255;
    return p;
  };
  bf16_t* wqkvT = (bf16_t*)take(3072ull * 1024 * 2);
  bf16_t* woT = (bf16_t*)take(1024ull * 1024 * 2);
  bf16_t* wfcT = (bf16_t*)take(4096ull * 1024 * 2);
  bf16_t* wprojT = (bf16_t*)take(1024ull * 4096 * 2);
  bf16_t* h = (bf16_t*)take(4096ull * 1024 * 2);
  bf16_t* qbuf = (bf16_t*)take(32ull * 2048 * 64 * 2);
  bf16_t* kbuf = (bf16_t*)take(32ull * 2048 * 64 * 2);
  bf16_t* vbuf = (bf16_t*)take(32ull * 2048 * 64 * 2);
  bf16_t* aout = (bf16_t*)take(4096ull * 1024 * 2);
  float* x2 = (float*)take(4096ull * 1024 * 4);
  bf16_t* mb = (bf16_t*)take(4096ull * 1024 * 2);
  // fc activation (32MB) aliases qbuf..aout (exactly 4 x 8MB), which are dead
  // by the time the FC GEMM runs.
  bf16_t* fca = (bf16_t*)qbuf;

  dim3 tb(32, 8);
  wtrans_kernel<<<dim3(3072 / 32, 1024 / 32), tb, 0, stream>>>(w_qkv, wqkvT, 1024, 3072);
  wtrans_kernel<<<dim3(1024 / 32, 1024 / 32), tb, 0, stream>>>(w_o, woT, 1024, 1024);
  wtrans_kernel<<<dim3(4096 / 32, 1024 / 32), tb, 0, stream>>>(w_fc, wfcT, 1024, 4096);
  wtrans_kernel<<<dim3(1024 / 32, 4096 / 32), tb, 0, stream>>>(w_proj, wprojT, 4096, 1024);

  ln_kernel<<<4096, 256, 0, stream>>>(x, ln1_g, ln1_b, pos_emb, h, 2048);

  gemm_bt<0><<<dim3(24, 32), 256, 0, stream>>>(h, wqkvT, b_qkv, nullptr, nullptr,
                                               nullptr, qbuf, kbuf, vbuf, 4096, 3072, 1024);

  attn_kernel<<<dim3(32, 32), 256, 0, stream>>>(qbuf, kbuf, vbuf, aout, 2048);

  gemm_bt<1><<<dim3(8, 32), 256, 0, stream>>>(aout, woT, b_o, x, x2, nullptr,
                                              nullptr, nullptr, nullptr, 4096, 1024, 1024);

  ln_kernel<<<4096, 256, 0, stream>>>(x2, ln2_g, ln2_b, nullptr, mb, 2048);

  gemm_bt<2><<<dim3(32, 32), 256, 0, stream>>>(mb, wfcT, b_fc, nullptr, nullptr,
                                               fca, nullptr, nullptr, nullptr, 4096, 4096, 1024);

  gemm_bt<1><<<dim3(8, 32), 256, 0, stream>>>(fca, wprojT, b_proj, x2, (float*)d_out,
                                              nullptr, nullptr, nullptr, nullptr, 4096, 1024, 4096);
}

// Round 4
// 452.237 us; speedup vs baseline: 1.0828x; 1.0828x over previous
//
#include <hip/hip_runtime.h>
#include <hip/hip_bf16.h>

typedef __hip_bfloat16 bf16_t;
typedef __bf16 bf16x8 __attribute__((ext_vector_type(8)));
typedef float f32x4 __attribute__((ext_vector_type(4)));

__device__ __forceinline__ void gload_lds16(const void* g, void* l) {
  __builtin_amdgcn_global_load_lds(
      (const __attribute__((address_space(1))) void*)g,
      (__attribute__((address_space(3))) void*)l, 16, 0, 0);
}

__device__ __forceinline__ unsigned short f2bf(float f) {
  bf16_t h = __float2bfloat16(f);
  return reinterpret_cast<unsigned short&>(h);
}

// ---------------- weight transpose: fp32 [K][N] -> bf16 [N][K] ----------------
__global__ __launch_bounds__(256) void wtrans_kernel(
    const float* __restrict__ in, bf16_t* __restrict__ out, int K, int N) {
  __shared__ float tile[32][33];
  int tx = threadIdx.x, ty = threadIdx.y;
  int n = blockIdx.x * 32 + tx;
  int k0 = blockIdx.y * 32 + ty;
#pragma unroll
  for (int j = 0; j < 32; j += 8) tile[ty + j][tx] = in[(size_t)(k0 + j) * N + n];
  __syncthreads();
  int k = blockIdx.y * 32 + tx;
  int n0 = blockIdx.x * 32 + ty;
#pragma unroll
  for (int j = 0; j < 32; j += 8)
    out[(size_t)(n0 + j) * K + k] = __float2bfloat16(tile[tx][ty + j]);
}

// ---------------- LayerNorm (+ optional pos_emb) -> bf16 ----------------
__global__ __launch_bounds__(256) void ln_kernel(
    const float* __restrict__ x, const float* __restrict__ g,
    const float* __restrict__ b, const float* __restrict__ pos,
    bf16_t* __restrict__ out, int S) {
  int row = blockIdx.x;
  int tid = threadIdx.x;
  const float4* xr = (const float4*)(x + (size_t)row * 1024);
  float4 v = xr[tid];
  float s1 = v.x + v.y + v.z + v.w;
  float s2 = v.x * v.x + v.y * v.y + v.z * v.z + v.w * v.w;
#pragma unroll
  for (int off = 1; off < 64; off <<= 1) {
    s1 += __shfl_xor(s1, off);
    s2 += __shfl_xor(s2, off);
  }
  __shared__ float red[2][4];
  int w = tid >> 6;
  if ((tid & 63) == 0) { red[0][w] = s1; red[1][w] = s2; }
  __syncthreads();
  s1 = red[0][0] + red[0][1] + red[0][2] + red[0][3];
  s2 = red[1][0] + red[1][1] + red[1][2] + red[1][3];
  float mu = s1 * (1.f / 1024.f);
  float var = s2 * (1.f / 1024.f) - mu * mu;
  float rs = rsqrtf(var + 1e-5f);
  float4 gg = ((const float4*)g)[tid];
  float4 bb = ((const float4*)b)[tid];
  float4 pp = {0.f, 0.f, 0.f, 0.f};
  if (pos) pp = ((const float4*)(pos + (size_t)(row & (S - 1)) * 1024))[tid];
  ushort4 o4;
  o4.x = f2bf((v.x - mu) * rs * gg.x + bb.x + pp.x);
  o4.y = f2bf((v.y - mu) * rs * gg.y + bb.y + pp.y);
  o4.z = f2bf((v.z - mu) * rs * gg.z + bb.z + pp.z);
  o4.w = f2bf((v.w - mu) * rs * gg.w + bb.w + pp.w);
  ((ushort4*)(out + (size_t)row * 1024))[tid] = o4;
}

// ---------------- GEMM: C[M,N] = A[M,K](bf16) * BT[N,K]^T(bf16) + bias ----------------
template <int EPI>
__global__ __launch_bounds__(256) void gemm_bt(
    const bf16_t* __restrict__ A, const bf16_t* __restrict__ BT,
    const float* __restrict__ bias, const float* __restrict__ resid,
    float* __restrict__ outf, bf16_t* __restrict__ outb,
    bf16_t* __restrict__ qb, bf16_t* __restrict__ kb, bf16_t* __restrict__ vb,
    int M, int N, int K) {
  __shared__ char lds[32768];
  char* As = lds;
  char* Bs = lds + 16384;
  int tid = threadIdx.x;
  int l = tid & 63;
  int w = tid >> 6;
  int wr = w >> 1, wc = w & 1;
  int ll = l & 15, lg = l >> 4;
  int rowBase = blockIdx.y * 128, colBase = blockIdx.x * 128;

  f32x4 acc[4][4];
  f32x4 z = {0.f, 0.f, 0.f, 0.f};
#pragma unroll
  for (int i = 0; i < 4; i++)
#pragma unroll
    for (int j = 0; j < 4; j++) acc[i][j] = z;

  int nkt = K >> 6;
  for (int kt = 0; kt < nkt; ++kt) {
    __syncthreads();
#pragma unroll
    for (int i = 0; i < 4; i++) {
      int p = i * 4096 + tid * 16;
      int o = p ^ (((p >> 7) & 7) << 4);
      int r = o >> 7, c = (o & 127) >> 1;
      gload_lds16(A + (size_t)(rowBase + r) * K + kt * 64 + c, As + p);
    }
#pragma unroll
    for (int i = 0; i < 4; i++) {
      int p = i * 4096 + tid * 16;
      int o = p ^ (((p >> 7) & 7) << 4);
      int r = o >> 7, c = (o & 127) >> 1;
      gload_lds16(BT + (size_t)(colBase + r) * K + kt * 64 + c, Bs + p);
    }
    __syncthreads();

    bf16x8 af[4][2], bfv[4][2];
#pragma unroll
    for (int mi = 0; mi < 4; mi++) {
      int row = wr * 64 + mi * 16 + ll;
#pragma unroll
      for (int kk = 0; kk < 2; kk++) {
        int o = (row << 7) + (kk << 6) + (lg << 4);
        af[mi][kk] = *(const bf16x8*)(As + (o ^ ((row & 7) << 4)));
      }
    }
#pragma unroll
    for (int ni = 0; ni < 4; ni++) {
      int row = wc * 64 + ni * 16 + ll;
#pragma unroll
      for (int kk = 0; kk < 2; kk++) {
        int o = (row << 7) + (kk << 6) + (lg << 4);
        bfv[ni][kk] = *(const bf16x8*)(Bs + (o ^ ((row & 7) << 4)));
      }
    }
#pragma unroll
    for (int mi = 0; mi < 4; mi++)
#pragma unroll
      for (int ni = 0; ni < 4; ni++)
#pragma unroll
        for (int kk = 0; kk < 2; kk++)
          acc[mi][ni] = __builtin_amdgcn_mfma_f32_16x16x32_bf16(
              af[mi][kk], bfv[ni][kk], acc[mi][ni], 0, 0, 0);
  }

  // epilogue
#pragma unroll
  for (int mi = 0; mi < 4; mi++) {
#pragma unroll
    for (int ni = 0; ni < 4; ni++) {
#pragma unroll
      for (int j = 0; j < 4; j++) {
        int grow = rowBase + wr * 64 + mi * 16 + lg * 4 + j;
        int gcol = colBase + wc * 64 + ni * 16 + ll;
        float v = acc[mi][ni][j] + bias[gcol];
        if (EPI == 0) {
          int bb = grow >> 11, s = grow & 2047;
          int t = gcol >> 10, rem = gcol & 1023;
          int h = rem >> 6, d = rem & 63;
          size_t bh = (size_t)(bb * 16 + h);
          if (t == 0)
            qb[(bh * 2048 + s) * 64 + d] = __float2bfloat16(v);
          else if (t == 1)
            kb[(bh * 2048 + s) * 64 + d] = __float2bfloat16(v);
          else
            vb[(bh * 64 + d) * 2048 + s] = __float2bfloat16(v);
        } else if (EPI == 1) {
          size_t idx = (size_t)grow * N + gcol;
          outf[idx] = resid[idx] + v;
        } else {
          float c3 = v * v * v;
          float t = tanhf(0.7978845608028654f * (v + 0.044715f * c3));
          outb[(size_t)grow * N + gcol] = __float2bfloat16(0.5f * v * (1.f + t));
        }
      }
    }
  }
}

// ---------------- flash attention (causal), HD=64, 128-row Q tiles ----------------
// 1-D grid of 512 blocks, heavy-first: bh = id&31, qt = 15 - id/32.
// 256 threads = 4 waves, each wave owns 32 q-rows.
// K/V double-buffered in LDS, staged via global_load_lds, counted vmcnt(4)
// so next-tile loads stay in flight across the raw s_barrier (T3/T4).
// q,k: [BH][S][64] bf16 ; vT: [BH][64][S] bf16 ; out: [B,S,1024] bf16
__global__ __launch_bounds__(256, 2) void attn_kernel(
    const bf16_t* __restrict__ qb, const bf16_t* __restrict__ kb,
    const bf16_t* __restrict__ vbT, bf16_t* __restrict__ op, int S) {
  int id = blockIdx.x;
  int bh = id & 31;
  int qt = 15 - (id >> 5);  // heavy-first dispatch order
  int tid = threadIdx.x;
  int w = tid >> 6, l = tid & 63;
  int ll = l & 15, lg = l >> 4;
  __shared__ char lds[49152];
  // K buffers: lds + c*8192 (64 k-rows x 64 d, bf16, swizzled)
  // V buffers: lds + 16384 + c*8192 (64 d x 64 s, bf16, swizzled)
  // P tile:    lds + 32768 + w*4096 (32 q-rows x 64 k, bf16, swizzled)
  char* Pw = lds + 32768 + w * 4096;

  int qbase = qt * 128;
  int qlo = qbase + w * 32;
  int qhi = qlo + 31;

  // Q fragments: 2 row-frags x 2 k-frags
  bf16x8 qf[2][2];
#pragma unroll
  for (int mi = 0; mi < 2; mi++) {
    const bf16_t* qrp = qb + ((size_t)bh * S + qbase + w * 32 + mi * 16 + ll) * 64;
#pragma unroll
    for (int kk = 0; kk < 2; kk++) qf[mi][kk] = *(const bf16x8*)(qrp + kk * 32 + lg * 8);
  }

  f32x4 Oacc[2][4];
  f32x4 z = {0.f, 0.f, 0.f, 0.f};
#pragma unroll
  for (int mi = 0; mi < 2; mi++)
#pragma unroll
    for (int i = 0; i < 4; i++) Oacc[mi][i] = z;
  float mrow[2][4], lrow[2][4];
#pragma unroll
  for (int mi = 0; mi < 2; mi++)
#pragma unroll
    for (int j = 0; j < 4; j++) { mrow[mi][j] = -INFINITY; lrow[mi][j] = 0.f; }

  int last = 2 * qt + 1;

  auto STAGE = [&](int kt, int c) {
    char* Kt = lds + c * 8192;
    char* Vt = lds + 16384 + c * 8192;
#pragma unroll
    for (int i = 0; i < 2; ++i) {
      int p = i * 4096 + tid * 16;
      int o = p ^ (((p >> 7) & 7) << 4);
      int r = o >> 7, cc = (o & 127) >> 1;
      gload_lds16(kb + ((size_t)bh * S + kt * 64 + r) * 64 + cc, Kt + p);
    }
#pragma unroll
    for (int i = 0; i < 2; ++i) {
      int p = i * 4096 + tid * 16;
      int o = p ^ (((p >> 7) & 7) << 4);
      int d = o >> 7, cc = (o & 127) >> 1;
      gload_lds16(vbT + ((size_t)bh * 64 + d) * S + kt * 64 + cc, Vt + p);
    }
  };

  STAGE(0, 0);
  int c = 0;
  for (int kt = 0; kt <= last; ++kt) {
    // all waves finished reading buf c^1 (their reads were consumed pre-barrier)
    __builtin_amdgcn_s_barrier();
    if (kt < last) {
      STAGE(kt + 1, c ^ 1);
      asm volatile("s_waitcnt vmcnt(4)" ::: "memory");  // own buf-c loads done
    } else {
      asm volatile("s_waitcnt vmcnt(0)" ::: "memory");
    }
    __builtin_amdgcn_s_barrier();  // everyone's buf-c loads landed
    asm volatile("" ::: "memory");  // keep LDS reads below the barrier

    if (kt * 64 <= qhi) {  // wave-uniform: skip fully-masked tiles
      char* Kt = lds + c * 8192;
      char* Vt = lds + 16384 + c * 8192;

      // --- S = Q K^T ---
      bf16x8 kf[4][2];
#pragma unroll
      for (int f = 0; f < 4; f++) {
        int row = f * 16 + ll;
#pragma unroll
        for (int kk = 0; kk < 2; kk++) {
          int o = (row << 7) + (kk << 6) + (lg << 4);
          kf[f][kk] = *(const bf16x8*)(Kt + (o ^ ((row & 7) << 4)));
        }
      }
      f32x4 sfr[2][4];
#pragma unroll
      for (int mi = 0; mi < 2; mi++)
#pragma unroll
        for (int f = 0; f < 4; f++) {
          sfr[mi][f] = z;
#pragma unroll
          for (int kk = 0; kk < 2; kk++)
            sfr[mi][f] = __builtin_amdgcn_mfma_f32_16x16x32_bf16(
                qf[mi][kk], kf[f][kk], sfr[mi][f], 0, 0, 0);
        }

      // --- online softmax ---
      bool diag = (kt * 64 + 63) > qlo;
#pragma unroll
      for (int mi = 0; mi < 2; mi++) {
#pragma unroll
        for (int j = 0; j < 4; j++) {
          int qr = qlo + mi * 16 + lg * 4 + j;  // global q row
          float mx = -INFINITY;
#pragma unroll
          for (int f = 0; f < 4; f++) {
            float s = sfr[mi][f][j] * 0.125f;
            if (diag && (kt * 64 + f * 16 + ll) > qr) s = -INFINITY;
            sfr[mi][f][j] = s;
            mx = fmaxf(mx, s);
          }
#pragma unroll
          for (int off = 1; off < 16; off <<= 1) mx = fmaxf(mx, __shfl_xor(mx, off));
          float mnew = fmaxf(mrow[mi][j], mx);
          float fj = __expf(mrow[mi][j] - mnew);
          float sum = 0.f;
#pragma unroll
          for (int f = 0; f < 4; f++) {
            float p = __expf(sfr[mi][f][j] - mnew);
            sfr[mi][f][j] = p;
            sum += p;
          }
#pragma unroll
          for (int off = 1; off < 16; off <<= 1) sum += __shfl_xor(sum, off);
          lrow[mi][j] = lrow[mi][j] * fj + sum;
          mrow[mi][j] = mnew;
#pragma unroll
          for (int fd = 0; fd < 4; fd++) Oacc[mi][fd][j] *= fj;
        }
      }

      // --- P -> per-wave LDS (swizzled) ---
#pragma unroll
      for (int mi = 0; mi < 2; mi++)
#pragma unroll
        for (int j = 0; j < 4; j++) {
          int r = mi * 16 + lg * 4 + j;
#pragma unroll
          for (int f = 0; f < 4; f++) {
            int o = (r << 7) + ((f * 16 + ll) << 1);
            *(unsigned short*)(Pw + (o ^ ((r & 7) << 4))) = f2bf(sfr[mi][f][j]);
          }
        }
      // per-wave tile: same wave reads it back; LDS ops in-order within wave,
      // compiler inserts lgkm waits via aliasing.

      // --- O += P V ---
      bf16x8 vf2[4][2];
#pragma unroll
      for (int fd = 0; fd < 4; fd++) {
        int row = fd * 16 + ll;
#pragma unroll
        for (int kk = 0; kk < 2; kk++) {
          int o = (row << 7) + (kk << 6) + (lg << 4);
          vf2[fd][kk] = *(const bf16x8*)(Vt + (o ^ ((row & 7) << 4)));
        }
      }
      bf16x8 pf[2][2];
#pragma unroll
      for (int mi = 0; mi < 2; mi++) {
        int pr = mi * 16 + ll;
#pragma unroll
        for (int kk = 0; kk < 2; kk++) {
          int o = (pr << 7) + (kk << 6) + (lg << 4);
          pf[mi][kk] = *(const bf16x8*)(Pw + (o ^ ((pr & 7) << 4)));
        }
      }
#pragma unroll
      for (int mi = 0; mi < 2; mi++)
#pragma unroll
        for (int fd = 0; fd < 4; fd++)
#pragma unroll
          for (int kk = 0; kk < 2; kk++)
            Oacc[mi][fd] = __builtin_amdgcn_mfma_f32_16x16x32_bf16(
                pf[mi][kk], vf2[fd][kk], Oacc[mi][fd], 0, 0, 0);
    }
    c ^= 1;
  }

  int b = bh >> 4, hh = bh & 15;
#pragma unroll
  for (int mi = 0; mi < 2; mi++)
#pragma unroll
    for (int j = 0; j < 4; j++) {
      int srow = qbase + w * 32 + mi * 16 + lg * 4 + j;
      float inv = 1.f / lrow[mi][j];
#pragma unroll
      for (int fd = 0; fd < 4; fd++) {
        int col = (hh << 6) + (fd << 4) + ll;
        op[((size_t)b * S + srow) * 1024 + col] = __float2bfloat16(Oacc[mi][fd][j] * inv);
      }
    }
}

// ---------------- launch ----------------
extern "C" void kernel_launch(void* const* d_in, const int* in_sizes, int n_in,
                              void* d_out, int out_size, void* d_ws, size_t ws_size,
                              hipStream_t stream) {
  const float* x = (const float*)d_in[0];
  const float* pos_emb = (const float*)d_in[1];
  const float* ln1_g = (const float*)d_in[2];
  const float* ln1_b = (const float*)d_in[3];
  const float* w_qkv = (const float*)d_in[4];
  const float* b_qkv = (const float*)d_in[5];
  const float* w_o = (const float*)d_in[6];
  const float* b_o = (const float*)d_in[7];
  const float* ln2_g = (const float*)d_in[8];
  const float* ln2_b = (const float*)d_in[9];
  const float* w_fc = (const float*)d_in[10];
  const float* b_fc = (const float*)d_in[11];
  const float* w_proj = (const float*)d_in[12];
  const float* b_proj = (const float*)d_in[13];

  char* ws = (char*)d_ws;
  auto take = [&](size_t bytes) {
    char* p = ws;
    ws += (bytes + 255) & ~(size_t)255;
    return p;
  };
  bf16_t* wqkvT = (bf16_t*)take(3072ull * 1024 * 2);
  bf16_t* woT = (bf16_t*)take(1024ull * 1024 * 2);
  bf16_t* wfcT = (bf16_t*)take(4096ull * 1024 * 2);
  bf16_t* wprojT = (bf16_t*)take(1024ull * 4096 * 2);
  bf16_t* h = (bf16_t*)take(4096ull * 1024 * 2);
  bf16_t* qbuf = (bf16_t*)take(32ull * 2048 * 64 * 2);
  bf16_t* kbuf = (bf16_t*)take(32ull * 2048 * 64 * 2);
  bf16_t* vbuf = (bf16_t*)take(32ull * 2048 * 64 * 2);
  bf16_t* aout = (bf16_t*)take(4096ull * 1024 * 2);
  float* x2 = (float*)take(4096ull * 1024 * 4);
  bf16_t* mb = (bf16_t*)take(4096ull * 1024 * 2);
  bf16_t* fca = (bf16_t*)qbuf;  // aliases dead q/k/v/aout buffers (32MB)

  dim3 tb(32, 8);
  wtrans_kernel<<<dim3(3072 / 32, 1024 / 32), tb, 0, stream>>>(w_qkv, wqkvT, 1024, 3072);
  wtrans_kernel<<<dim3(1024 / 32, 1024 / 32), tb, 0, stream>>>(w_o, woT, 1024, 1024);
  wtrans_kernel<<<dim3(4096 / 32, 1024 / 32), tb, 0, stream>>>(w_fc, wfcT, 1024, 4096);
  wtrans_kernel<<<dim3(1024 / 32, 4096 / 32), tb, 0, stream>>>(w_proj, wprojT, 4096, 1024);

  ln_kernel<<<4096, 256, 0, stream>>>(x, ln1_g, ln1_b, pos_emb, h, 2048);

  gemm_bt<0><<<dim3(24, 32), 256, 0, stream>>>(h, wqkvT, b_qkv, nullptr, nullptr,
                                               nullptr, qbuf, kbuf, vbuf, 4096, 3072, 1024);

  attn_kernel<<<dim3(512), 256, 0, stream>>>(qbuf, kbuf, vbuf, aout, 2048);

  gemm_bt<1><<<dim3(8, 32), 256, 0, stream>>>(aout, woT, b_o, x, x2, nullptr,
                                              nullptr, nullptr, nullptr, 4096, 1024, 1024);

  ln_kernel<<<4096, 256, 0, stream>>>(x2, ln2_g, ln2_b, nullptr, mb, 2048);

  gemm_bt<2><<<dim3(32, 32), 256, 0, stream>>>(mb, wfcT, b_fc, nullptr, nullptr,
                                               fca, nullptr, nullptr, nullptr, 4096, 4096, 1024);

  gemm_bt<1><<<dim3(8, 32), 256, 0, stream>>>(fca, wprojT, b_proj, x2, (float*)d_out,
                                              nullptr, nullptr, nullptr, nullptr, 4096, 1024, 4096);
}

// Round 5
// 417.195 us; speedup vs baseline: 1.1737x; 1.0840x over previous
//
#include <hip/hip_runtime.h>
#include <hip/hip_bf16.h>

typedef __hip_bfloat16 bf16_t;
typedef __bf16 bf16x8 __attribute__((ext_vector_type(8)));
typedef float f32x4 __attribute__((ext_vector_type(4)));

__device__ __forceinline__ void gload_lds16(const void* g, void* l) {
  __builtin_amdgcn_global_load_lds(
      (const __attribute__((address_space(1))) void*)g,
      (__attribute__((address_space(3))) void*)l, 16, 0, 0);
}

__device__ __forceinline__ unsigned short f2bf(float f) {
  bf16_t h = __float2bfloat16(f);
  return reinterpret_cast<unsigned short&>(h);
}

// ---------------- weight transpose: fp32 [K][N] -> bf16 [N][K] ----------------
__global__ __launch_bounds__(256) void wtrans_kernel(
    const float* __restrict__ in, bf16_t* __restrict__ out, int K, int N) {
  __shared__ float tile[32][33];
  int tx = threadIdx.x, ty = threadIdx.y;
  int n = blockIdx.x * 32 + tx;
  int k0 = blockIdx.y * 32 + ty;
#pragma unroll
  for (int j = 0; j < 32; j += 8) tile[ty + j][tx] = in[(size_t)(k0 + j) * N + n];
  __syncthreads();
  int k = blockIdx.y * 32 + tx;
  int n0 = blockIdx.x * 32 + ty;
#pragma unroll
  for (int j = 0; j < 32; j += 8)
    out[(size_t)(n0 + j) * K + k] = __float2bfloat16(tile[tx][ty + j]);
}

// ---------------- LayerNorm (+ optional pos_emb) -> bf16 ----------------
__global__ __launch_bounds__(256) void ln_kernel(
    const float* __restrict__ x, const float* __restrict__ g,
    const float* __restrict__ b, const float* __restrict__ pos,
    bf16_t* __restrict__ out, int S) {
  int row = blockIdx.x;
  int tid = threadIdx.x;
  const float4* xr = (const float4*)(x + (size_t)row * 1024);
  float4 v = xr[tid];
  float s1 = v.x + v.y + v.z + v.w;
  float s2 = v.x * v.x + v.y * v.y + v.z * v.z + v.w * v.w;
#pragma unroll
  for (int off = 1; off < 64; off <<= 1) {
    s1 += __shfl_xor(s1, off);
    s2 += __shfl_xor(s2, off);
  }
  __shared__ float red[2][4];
  int w = tid >> 6;
  if ((tid & 63) == 0) { red[0][w] = s1; red[1][w] = s2; }
  __syncthreads();
  s1 = red[0][0] + red[0][1] + red[0][2] + red[0][3];
  s2 = red[1][0] + red[1][1] + red[1][2] + red[1][3];
  float mu = s1 * (1.f / 1024.f);
  float var = s2 * (1.f / 1024.f) - mu * mu;
  float rs = rsqrtf(var + 1e-5f);
  float4 gg = ((const float4*)g)[tid];
  float4 bb = ((const float4*)b)[tid];
  float4 pp = {0.f, 0.f, 0.f, 0.f};
  if (pos) pp = ((const float4*)(pos + (size_t)(row & (S - 1)) * 1024))[tid];
  ushort4 o4;
  o4.x = f2bf((v.x - mu) * rs * gg.x + bb.x + pp.x);
  o4.y = f2bf((v.y - mu) * rs * gg.y + bb.y + pp.y);
  o4.z = f2bf((v.z - mu) * rs * gg.z + bb.z + pp.z);
  o4.w = f2bf((v.w - mu) * rs * gg.w + bb.w + pp.w);
  ((ushort4*)(out + (size_t)row * 1024))[tid] = o4;
}

// ---------------- GEMM: C[M,N] = A[M,K](bf16) * BT[N,K]^T(bf16) + bias ----------------
// 128x128 tile, BK=64, 256 threads (4 waves, 2x2), mfma 16x16x32 bf16.
// DBUF=1: 64KB double-buffered LDS, counted vmcnt(8) so next-tile loads stay in
// flight across the barrier (attn-proven pattern). Use ONLY for 1-block/CU
// dispatches (no occupancy to lose; m132 warns 64KB LDS hurts 3-4 block/CU).
// EPI: 0 = QKV scatter, 1 = out_f32 = resid + acc + bias, 2 = gelu -> bf16
template <int EPI, int DBUF>
__global__ __launch_bounds__(256) void gemm_bt(
    const bf16_t* __restrict__ A, const bf16_t* __restrict__ BT,
    const float* __restrict__ bias, const float* __restrict__ resid,
    float* __restrict__ outf, bf16_t* __restrict__ outb,
    bf16_t* __restrict__ qb, bf16_t* __restrict__ kb, bf16_t* __restrict__ vb,
    int M, int N, int K) {
  __shared__ char lds[DBUF ? 65536 : 32768];
  int tid = threadIdx.x;
  int l = tid & 63;
  int w = tid >> 6;
  int wr = w >> 1, wc = w & 1;
  int ll = l & 15, lg = l >> 4;
  int rowBase = blockIdx.y * 128, colBase = blockIdx.x * 128;

  f32x4 acc[4][4];
  f32x4 z = {0.f, 0.f, 0.f, 0.f};
#pragma unroll
  for (int i = 0; i < 4; i++)
#pragma unroll
    for (int j = 0; j < 4; j++) acc[i][j] = z;

  auto STAGE = [&](int kt, int c) {
#pragma unroll
    for (int i = 0; i < 4; i++) {
      int p = i * 4096 + tid * 16;
      int o = p ^ (((p >> 7) & 7) << 4);
      int r = o >> 7, cc = (o & 127) >> 1;
      gload_lds16(A + (size_t)(rowBase + r) * K + kt * 64 + cc, lds + c * 32768 + p);
    }
#pragma unroll
    for (int i = 0; i < 4; i++) {
      int p = i * 4096 + tid * 16;
      int o = p ^ (((p >> 7) & 7) << 4);
      int r = o >> 7, cc = (o & 127) >> 1;
      gload_lds16(BT + (size_t)(colBase + r) * K + kt * 64 + cc,
                  lds + c * 32768 + 16384 + p);
    }
  };

  int nkt = K >> 6;
  if (DBUF) STAGE(0, 0);
  int cbuf = 0;
  for (int kt = 0; kt < nkt; ++kt) {
    if (DBUF) {
      __builtin_amdgcn_s_barrier();  // all waves done reading buf cbuf^1
      if (kt + 1 < nkt) {
        STAGE(kt + 1, cbuf ^ 1);
        asm volatile("s_waitcnt vmcnt(8)" ::: "memory");  // own buf-cbuf loads done
      } else {
        asm volatile("s_waitcnt vmcnt(0)" ::: "memory");
      }
      __builtin_amdgcn_s_barrier();  // everyone's buf-cbuf loads landed
      asm volatile("" ::: "memory");
    } else {
      __syncthreads();
      STAGE(kt, 0);
      __syncthreads();
    }
    char* Ab = lds + cbuf * 32768;
    char* Bb = Ab + 16384;

    bf16x8 af[4][2], bfv[4][2];
#pragma unroll
    for (int mi = 0; mi < 4; mi++) {
      int row = wr * 64 + mi * 16 + ll;
#pragma unroll
      for (int kk = 0; kk < 2; kk++) {
        int o = (row << 7) + (kk << 6) + (lg << 4);
        af[mi][kk] = *(const bf16x8*)(Ab + (o ^ ((row & 7) << 4)));
      }
    }
#pragma unroll
    for (int ni = 0; ni < 4; ni++) {
      int row = wc * 64 + ni * 16 + ll;
#pragma unroll
      for (int kk = 0; kk < 2; kk++) {
        int o = (row << 7) + (kk << 6) + (lg << 4);
        bfv[ni][kk] = *(const bf16x8*)(Bb + (o ^ ((row & 7) << 4)));
      }
    }
#pragma unroll
    for (int mi = 0; mi < 4; mi++)
#pragma unroll
      for (int ni = 0; ni < 4; ni++)
#pragma unroll
        for (int kk = 0; kk < 2; kk++)
          acc[mi][ni] = __builtin_amdgcn_mfma_f32_16x16x32_bf16(
              af[mi][kk], bfv[ni][kk], acc[mi][ni], 0, 0, 0);
    if (DBUF) cbuf ^= 1;
  }

  // epilogue
#pragma unroll
  for (int mi = 0; mi < 4; mi++) {
#pragma unroll
    for (int ni = 0; ni < 4; ni++) {
#pragma unroll
      for (int j = 0; j < 4; j++) {
        int grow = rowBase + wr * 64 + mi * 16 + lg * 4 + j;
        int gcol = colBase + wc * 64 + ni * 16 + ll;
        float v = acc[mi][ni][j] + bias[gcol];
        if (EPI == 0) {
          int bb = grow >> 11, s = grow & 2047;
          int t = gcol >> 10, rem = gcol & 1023;
          int h = rem >> 6, d = rem & 63;
          size_t bh = (size_t)(bb * 16 + h);
          if (t == 0)
            qb[(bh * 2048 + s) * 64 + d] = __float2bfloat16(v);
          else if (t == 1)
            kb[(bh * 2048 + s) * 64 + d] = __float2bfloat16(v);
          else
            vb[(bh * 64 + d) * 2048 + s] = __float2bfloat16(v);
        } else if (EPI == 1) {
          size_t idx = (size_t)grow * N + gcol;
          outf[idx] = resid[idx] + v;
        } else {
          float c3 = v * v * v;
          float t = tanhf(0.7978845608028654f * (v + 0.044715f * c3));
          outb[(size_t)grow * N + gcol] = __float2bfloat16(0.5f * v * (1.f + t));
        }
      }
    }
  }
}

// ---------------- flash attention (causal), HD=64, 128-row Q tiles ----------------
// 1-D grid of 512 blocks, heavy-first: bh = id&31, qt = 15 - id/32.
// 256 threads = 4 waves, each wave owns 32 q-rows.
// K/V double-buffered in LDS, staged via global_load_lds, counted vmcnt(4)
// so next-tile loads stay in flight across the raw s_barrier (T3/T4).
// q,k: [BH][S][64] bf16 ; vT: [BH][64][S] bf16 ; out: [B,S,1024] bf16
__global__ __launch_bounds__(256, 2) void attn_kernel(
    const bf16_t* __restrict__ qb, const bf16_t* __restrict__ kb,
    const bf16_t* __restrict__ vbT, bf16_t* __restrict__ op, int S) {
  int id = blockIdx.x;
  int bh = id & 31;
  int qt = 15 - (id >> 5);  // heavy-first dispatch order
  int tid = threadIdx.x;
  int w = tid >> 6, l = tid & 63;
  int ll = l & 15, lg = l >> 4;
  __shared__ char lds[49152];
  char* Pw = lds + 32768 + w * 4096;

  int qbase = qt * 128;
  int qlo = qbase + w * 32;
  int qhi = qlo + 31;

  bf16x8 qf[2][2];
#pragma unroll
  for (int mi = 0; mi < 2; mi++) {
    const bf16_t* qrp = qb + ((size_t)bh * S + qbase + w * 32 + mi * 16 + ll) * 64;
#pragma unroll
    for (int kk = 0; kk < 2; kk++) qf[mi][kk] = *(const bf16x8*)(qrp + kk * 32 + lg * 8);
  }

  f32x4 Oacc[2][4];
  f32x4 z = {0.f, 0.f, 0.f, 0.f};
#pragma unroll
  for (int mi = 0; mi < 2; mi++)
#pragma unroll
    for (int i = 0; i < 4; i++) Oacc[mi][i] = z;
  float mrow[2][4], lrow[2][4];
#pragma unroll
  for (int mi = 0; mi < 2; mi++)
#pragma unroll
    for (int j = 0; j < 4; j++) { mrow[mi][j] = -INFINITY; lrow[mi][j] = 0.f; }

  int last = 2 * qt + 1;

  auto STAGE = [&](int kt, int c) {
    char* Kt = lds + c * 8192;
    char* Vt = lds + 16384 + c * 8192;
#pragma unroll
    for (int i = 0; i < 2; ++i) {
      int p = i * 4096 + tid * 16;
      int o = p ^ (((p >> 7) & 7) << 4);
      int r = o >> 7, cc = (o & 127) >> 1;
      gload_lds16(kb + ((size_t)bh * S + kt * 64 + r) * 64 + cc, Kt + p);
    }
#pragma unroll
    for (int i = 0; i < 2; ++i) {
      int p = i * 4096 + tid * 16;
      int o = p ^ (((p >> 7) & 7) << 4);
      int d = o >> 7, cc = (o & 127) >> 1;
      gload_lds16(vbT + ((size_t)bh * 64 + d) * S + kt * 64 + cc, Vt + p);
    }
  };

  STAGE(0, 0);
  int c = 0;
  for (int kt = 0; kt <= last; ++kt) {
    __builtin_amdgcn_s_barrier();
    if (kt < last) {
      STAGE(kt + 1, c ^ 1);
      asm volatile("s_waitcnt vmcnt(4)" ::: "memory");
    } else {
      asm volatile("s_waitcnt vmcnt(0)" ::: "memory");
    }
    __builtin_amdgcn_s_barrier();
    asm volatile("" ::: "memory");

    if (kt * 64 <= qhi) {
      char* Kt = lds + c * 8192;
      char* Vt = lds + 16384 + c * 8192;

      bf16x8 kf[4][2];
#pragma unroll
      for (int f = 0; f < 4; f++) {
        int row = f * 16 + ll;
#pragma unroll
        for (int kk = 0; kk < 2; kk++) {
          int o = (row << 7) + (kk << 6) + (lg << 4);
          kf[f][kk] = *(const bf16x8*)(Kt + (o ^ ((row & 7) << 4)));
        }
      }
      f32x4 sfr[2][4];
#pragma unroll
      for (int mi = 0; mi < 2; mi++)
#pragma unroll
        for (int f = 0; f < 4; f++) {
          sfr[mi][f] = z;
#pragma unroll
          for (int kk = 0; kk < 2; kk++)
            sfr[mi][f] = __builtin_amdgcn_mfma_f32_16x16x32_bf16(
                qf[mi][kk], kf[f][kk], sfr[mi][f], 0, 0, 0);
        }

      bool diag = (kt * 64 + 63) > qlo;
#pragma unroll
      for (int mi = 0; mi < 2; mi++) {
#pragma unroll
        for (int j = 0; j < 4; j++) {
          int qr = qlo + mi * 16 + lg * 4 + j;
          float mx = -INFINITY;
#pragma unroll
          for (int f = 0; f < 4; f++) {
            float s = sfr[mi][f][j] * 0.125f;
            if (diag && (kt * 64 + f * 16 + ll) > qr) s = -INFINITY;
            sfr[mi][f][j] = s;
            mx = fmaxf(mx, s);
          }
#pragma unroll
          for (int off = 1; off < 16; off <<= 1) mx = fmaxf(mx, __shfl_xor(mx, off));
          float mnew = fmaxf(mrow[mi][j], mx);
          float fj = __expf(mrow[mi][j] - mnew);
          float sum = 0.f;
#pragma unroll
          for (int f = 0; f < 4; f++) {
            float p = __expf(sfr[mi][f][j] - mnew);
            sfr[mi][f][j] = p;
            sum += p;
          }
#pragma unroll
          for (int off = 1; off < 16; off <<= 1) sum += __shfl_xor(sum, off);
          lrow[mi][j] = lrow[mi][j] * fj + sum;
          mrow[mi][j] = mnew;
#pragma unroll
          for (int fd = 0; fd < 4; fd++) Oacc[mi][fd][j] *= fj;
        }
      }

#pragma unroll
      for (int mi = 0; mi < 2; mi++)
#pragma unroll
        for (int j = 0; j < 4; j++) {
          int r = mi * 16 + lg * 4 + j;
#pragma unroll
          for (int f = 0; f < 4; f++) {
            int o = (r << 7) + ((f * 16 + ll) << 1);
            *(unsigned short*)(Pw + (o ^ ((r & 7) << 4))) = f2bf(sfr[mi][f][j]);
          }
        }

      bf16x8 vf2[4][2];
#pragma unroll
      for (int fd = 0; fd < 4; fd++) {
        int row = fd * 16 + ll;
#pragma unroll
        for (int kk = 0; kk < 2; kk++) {
          int o = (row << 7) + (kk << 6) + (lg << 4);
          vf2[fd][kk] = *(const bf16x8*)(Vt + (o ^ ((row & 7) << 4)));
        }
      }
      bf16x8 pf[2][2];
#pragma unroll
      for (int mi = 0; mi < 2; mi++) {
        int pr = mi * 16 + ll;
#pragma unroll
        for (int kk = 0; kk < 2; kk++) {
          int o = (pr << 7) + (kk << 6) + (lg << 4);
          pf[mi][kk] = *(const bf16x8*)(Pw + (o ^ ((pr & 7) << 4)));
        }
      }
#pragma unroll
      for (int mi = 0; mi < 2; mi++)
#pragma unroll
        for (int fd = 0; fd < 4; fd++)
#pragma unroll
          for (int kk = 0; kk < 2; kk++)
            Oacc[mi][fd] = __builtin_amdgcn_mfma_f32_16x16x32_bf16(
                pf[mi][kk], vf2[fd][kk], Oacc[mi][fd], 0, 0, 0);
    }
    c ^= 1;
  }

  int b = bh >> 4, hh = bh & 15;
#pragma unroll
  for (int mi = 0; mi < 2; mi++)
#pragma unroll
    for (int j = 0; j < 4; j++) {
      int srow = qbase + w * 32 + mi * 16 + lg * 4 + j;
      float inv = 1.f / lrow[mi][j];
#pragma unroll
      for (int fd = 0; fd < 4; fd++) {
        int col = (hh << 6) + (fd << 4) + ll;
        op[((size_t)b * S + srow) * 1024 + col] = __float2bfloat16(Oacc[mi][fd][j] * inv);
      }
    }
}

// ---------------- launch ----------------
extern "C" void kernel_launch(void* const* d_in, const int* in_sizes, int n_in,
                              void* d_out, int out_size, void* d_ws, size_t ws_size,
                              hipStream_t stream) {
  const float* x = (const float*)d_in[0];
  const float* pos_emb = (const float*)d_in[1];
  const float* ln1_g = (const float*)d_in[2];
  const float* ln1_b = (const float*)d_in[3];
  const float* w_qkv = (const float*)d_in[4];
  const float* b_qkv = (const float*)d_in[5];
  const float* w_o = (const float*)d_in[6];
  const float* b_o = (const float*)d_in[7];
  const float* ln2_g = (const float*)d_in[8];
  const float* ln2_b = (const float*)d_in[9];
  const float* w_fc = (const float*)d_in[10];
  const float* b_fc = (const float*)d_in[11];
  const float* w_proj = (const float*)d_in[12];
  const float* b_proj = (const float*)d_in[13];

  char* ws = (char*)d_ws;
  auto take = [&](size_t bytes) {
    char* p = ws;
    ws += (bytes + 255) & ~(size_t)255;
    return p;
  };
  bf16_t* wqkvT = (bf16_t*)take(3072ull * 1024 * 2);
  bf16_t* woT = (bf16_t*)take(1024ull * 1024 * 2);
  bf16_t* wfcT = (bf16_t*)take(4096ull * 1024 * 2);
  bf16_t* wprojT = (bf16_t*)take(1024ull * 4096 * 2);
  bf16_t* h = (bf16_t*)take(4096ull * 1024 * 2);
  bf16_t* qbuf = (bf16_t*)take(32ull * 2048 * 64 * 2);
  bf16_t* kbuf = (bf16_t*)take(32ull * 2048 * 64 * 2);
  bf16_t* vbuf = (bf16_t*)take(32ull * 2048 * 64 * 2);
  bf16_t* aout = (bf16_t*)take(4096ull * 1024 * 2);
  float* x2 = (float*)take(4096ull * 1024 * 4);
  bf16_t* mb = (bf16_t*)take(4096ull * 1024 * 2);
  bf16_t* fca = (bf16_t*)qbuf;  // aliases dead q/k/v/aout buffers (32MB)

  dim3 tb(32, 8);
  wtrans_kernel<<<dim3(3072 / 32, 1024 / 32), tb, 0, stream>>>(w_qkv, wqkvT, 1024, 3072);
  wtrans_kernel<<<dim3(1024 / 32, 1024 / 32), tb, 0, stream>>>(w_o, woT, 1024, 1024);
  wtrans_kernel<<<dim3(4096 / 32, 1024 / 32), tb, 0, stream>>>(w_fc, wfcT, 1024, 4096);
  wtrans_kernel<<<dim3(1024 / 32, 4096 / 32), tb, 0, stream>>>(w_proj, wprojT, 4096, 1024);

  ln_kernel<<<4096, 256, 0, stream>>>(x, ln1_g, ln1_b, pos_emb, h, 2048);

  gemm_bt<0, 0><<<dim3(24, 32), 256, 0, stream>>>(h, wqkvT, b_qkv, nullptr, nullptr,
                                                  nullptr, qbuf, kbuf, vbuf, 4096, 3072, 1024);

  attn_kernel<<<dim3(512), 256, 0, stream>>>(qbuf, kbuf, vbuf, aout, 2048);

  gemm_bt<1, 1><<<dim3(8, 32), 256, 0, stream>>>(aout, woT, b_o, x, x2, nullptr,
                                                 nullptr, nullptr, nullptr, 4096, 1024, 1024);

  ln_kernel<<<4096, 256, 0, stream>>>(x2, ln2_g, ln2_b, nullptr, mb, 2048);

  gemm_bt<2, 0><<<dim3(32, 32), 256, 0, stream>>>(mb, wfcT, b_fc, nullptr, nullptr,
                                                  fca, nullptr, nullptr, nullptr, 4096, 4096, 1024);

  gemm_bt<1, 1><<<dim3(8, 32), 256, 0, stream>>>(fca, wprojT, b_proj, x2, (float*)d_out,
                                                 nullptr, nullptr, nullptr, nullptr, 4096, 1024, 4096);
}

// Round 7
// 380.528 us; speedup vs baseline: 1.2868x; 1.0964x over previous
//
#include <hip/hip_runtime.h>
#include <hip/hip_bf16.h>

typedef __hip_bfloat16 bf16_t;
typedef __bf16 bf16x8 __attribute__((ext_vector_type(8)));
typedef float f32x4 __attribute__((ext_vector_type(4)));

__device__ __forceinline__ void gload_lds16(const void* g, void* l) {
  __builtin_amdgcn_global_load_lds(
      (const __attribute__((address_space(1))) void*)g,
      (__attribute__((address_space(3))) void*)l, 16, 0, 0);
}

__device__ __forceinline__ unsigned short f2bf(float f) {
  bf16_t h = __float2bfloat16(f);
  return reinterpret_cast<unsigned short&>(h);
}

// ---------------- weight transpose: fp32 [K][N] -> bf16 [N][K] ----------------
__global__ __launch_bounds__(256) void wtrans_kernel(
    const float* __restrict__ in, bf16_t* __restrict__ out, int K, int N) {
  __shared__ float tile[32][33];
  int tx = threadIdx.x, ty = threadIdx.y;
  int n = blockIdx.x * 32 + tx;
  int k0 = blockIdx.y * 32 + ty;
#pragma unroll
  for (int j = 0; j < 32; j += 8) tile[ty + j][tx] = in[(size_t)(k0 + j) * N + n];
  __syncthreads();
  int k = blockIdx.y * 32 + tx;
  int n0 = blockIdx.x * 32 + ty;
#pragma unroll
  for (int j = 0; j < 32; j += 8)
    out[(size_t)(n0 + j) * K + k] = __float2bfloat16(tile[tx][ty + j]);
}

// ---------------- LayerNorm (+ optional pos_emb) -> bf16 ----------------
__global__ __launch_bounds__(256) void ln_kernel(
    const float* __restrict__ x, const float* __restrict__ g,
    const float* __restrict__ b, const float* __restrict__ pos,
    bf16_t* __restrict__ out, int S) {
  int row = blockIdx.x;
  int tid = threadIdx.x;
  const float4* xr = (const float4*)(x + (size_t)row * 1024);
  float4 v = xr[tid];
  float s1 = v.x + v.y + v.z + v.w;
  float s2 = v.x * v.x + v.y * v.y + v.z * v.z + v.w * v.w;
#pragma unroll
  for (int off = 1; off < 64; off <<= 1) {
    s1 += __shfl_xor(s1, off);
    s2 += __shfl_xor(s2, off);
  }
  __shared__ float red[2][4];
  int w = tid >> 6;
  if ((tid & 63) == 0) { red[0][w] = s1; red[1][w] = s2; }
  __syncthreads();
  s1 = red[0][0] + red[0][1] + red[0][2] + red[0][3];
  s2 = red[1][0] + red[1][1] + red[1][2] + red[1][3];
  float mu = s1 * (1.f / 1024.f);
  float var = s2 * (1.f / 1024.f) - mu * mu;
  float rs = rsqrtf(var + 1e-5f);
  float4 gg = ((const float4*)g)[tid];
  float4 bb = ((const float4*)b)[tid];
  float4 pp = {0.f, 0.f, 0.f, 0.f};
  if (pos) pp = ((const float4*)(pos + (size_t)(row & (S - 1)) * 1024))[tid];
  ushort4 o4;
  o4.x = f2bf((v.x - mu) * rs * gg.x + bb.x + pp.x);
  o4.y = f2bf((v.y - mu) * rs * gg.y + bb.y + pp.y);
  o4.z = f2bf((v.z - mu) * rs * gg.z + bb.z + pp.z);
  o4.w = f2bf((v.w - mu) * rs * gg.w + bb.w + pp.w);
  ((ushort4*)(out + (size_t)row * 1024))[tid] = o4;
}

// ---------------- GEMM: C[M,N] = A[M,K](bf16) * BT[N,K]^T(bf16) + bias ----------------
// 1-D grid with bijective XCD-chunked swizzle (T1): grid size must be %8==0.
// DBUF=1: 64KB double-buffered LDS + counted vmcnt(8) (for 1-block/CU dispatches).
template <int EPI, int DBUF>
__global__ __launch_bounds__(256) void gemm_bt(
    const bf16_t* __restrict__ A, const bf16_t* __restrict__ BT,
    const float* __restrict__ bias, const float* __restrict__ resid,
    float* __restrict__ outf, bf16_t* __restrict__ outb,
    bf16_t* __restrict__ qb, bf16_t* __restrict__ kb, bf16_t* __restrict__ vb,
    int M, int N, int K) {
  __shared__ char lds[DBUF ? 65536 : 32768];
  int tid = threadIdx.x;
  int l = tid & 63;
  int w = tid >> 6;
  int wr = w >> 1, wc = w & 1;
  int ll = l & 15, lg = l >> 4;
  // XCD-chunked swizzle: consecutive swz ids stay on one XCD, share A-panels.
  int chunk = gridDim.x >> 3;
  int swz = (blockIdx.x & 7) * chunk + (blockIdx.x >> 3);
  int nbx = N >> 7;
  int bx = swz % nbx, by = swz / nbx;
  int rowBase = by * 128, colBase = bx * 128;

  f32x4 acc[4][4];
  f32x4 z = {0.f, 0.f, 0.f, 0.f};
#pragma unroll
  for (int i = 0; i < 4; i++)
#pragma unroll
    for (int j = 0; j < 4; j++) acc[i][j] = z;

  auto STAGE = [&](int kt, int c) {
#pragma unroll
    for (int i = 0; i < 4; i++) {
      int p = i * 4096 + tid * 16;
      int o = p ^ (((p >> 7) & 7) << 4);
      int r = o >> 7, cc = (o & 127) >> 1;
      gload_lds16(A + (size_t)(rowBase + r) * K + kt * 64 + cc, lds + c * 32768 + p);
    }
#pragma unroll
    for (int i = 0; i < 4; i++) {
      int p = i * 4096 + tid * 16;
      int o = p ^ (((p >> 7) & 7) << 4);
      int r = o >> 7, cc = (o & 127) >> 1;
      gload_lds16(BT + (size_t)(colBase + r) * K + kt * 64 + cc,
                  lds + c * 32768 + 16384 + p);
    }
  };

  int nkt = K >> 6;
  if (DBUF) STAGE(0, 0);
  int cbuf = 0;
  for (int kt = 0; kt < nkt; ++kt) {
    if (DBUF) {
      __builtin_amdgcn_s_barrier();  // all waves done reading buf cbuf^1
      if (kt + 1 < nkt) {
        STAGE(kt + 1, cbuf ^ 1);
        asm volatile("s_waitcnt vmcnt(8)" ::: "memory");  // own buf-cbuf loads done
      } else {
        asm volatile("s_waitcnt vmcnt(0)" ::: "memory");
      }
      __builtin_amdgcn_s_barrier();  // everyone's buf-cbuf loads landed
      asm volatile("" ::: "memory");
    } else {
      __syncthreads();
      STAGE(kt, 0);
      __syncthreads();
    }
    char* Ab = lds + cbuf * 32768;
    char* Bb = Ab + 16384;

    bf16x8 af[4][2], bfv[4][2];
#pragma unroll
    for (int mi = 0; mi < 4; mi++) {
      int row = wr * 64 + mi * 16 + ll;
#pragma unroll
      for (int kk = 0; kk < 2; kk++) {
        int o = (row << 7) + (kk << 6) + (lg << 4);
        af[mi][kk] = *(const bf16x8*)(Ab + (o ^ ((row & 7) << 4)));
      }
    }
#pragma unroll
    for (int ni = 0; ni < 4; ni++) {
      int row = wc * 64 + ni * 16 + ll;
#pragma unroll
      for (int kk = 0; kk < 2; kk++) {
        int o = (row << 7) + (kk << 6) + (lg << 4);
        bfv[ni][kk] = *(const bf16x8*)(Bb + (o ^ ((row & 7) << 4)));
      }
    }
#pragma unroll
    for (int mi = 0; mi < 4; mi++)
#pragma unroll
      for (int ni = 0; ni < 4; ni++)
#pragma unroll
        for (int kk = 0; kk < 2; kk++)
          acc[mi][ni] = __builtin_amdgcn_mfma_f32_16x16x32_bf16(
              af[mi][kk], bfv[ni][kk], acc[mi][ni], 0, 0, 0);
    if (DBUF) cbuf ^= 1;
  }

  // epilogue
#pragma unroll
  for (int mi = 0; mi < 4; mi++) {
#pragma unroll
    for (int ni = 0; ni < 4; ni++) {
#pragma unroll
      for (int j = 0; j < 4; j++) {
        int grow = rowBase + wr * 64 + mi * 16 + lg * 4 + j;
        int gcol = colBase + wc * 64 + ni * 16 + ll;
        float v = acc[mi][ni][j] + bias[gcol];
        if (EPI == 0) {
          int bb = grow >> 11, s = grow & 2047;
          int t = gcol >> 10, rem = gcol & 1023;
          int h = rem >> 6, d = rem & 63;
          size_t bh = (size_t)(bb * 16 + h);
          if (t == 0)
            qb[(bh * 2048 + s) * 64 + d] = __float2bfloat16(v);
          else if (t == 1)
            kb[(bh * 2048 + s) * 64 + d] = __float2bfloat16(v);
          else
            vb[(bh * 64 + d) * 2048 + s] = __float2bfloat16(v);
        } else if (EPI == 1) {
          size_t idx = (size_t)grow * N + gcol;
          outf[idx] = resid[idx] + v;
        } else {
          float c3 = v * v * v;
          float t = tanhf(0.7978845608028654f * (v + 0.044715f * c3));
          outb[(size_t)grow * N + gcol] = __float2bfloat16(0.5f * v * (1.f + t));
        }
      }
    }
  }
}

// ---------------- flash attention (causal), HD=64, 128-row Q tiles ----------------
// Swapped-QK^T: S^T = mfma(A=K, B=Q) puts 16 of each q-row's scores IN-LANE
// (k = f*16+lg*4+j, q = ll) -> softmax reduce = in-lane fmax/add + 2 shuffles
// (was 8 shuffles per row). T13 defer-rescale; T5 setprio around MFMA clusters.
__global__ __launch_bounds__(256, 2) void attn_kernel(
    const bf16_t* __restrict__ qb, const bf16_t* __restrict__ kb,
    const bf16_t* __restrict__ vbT, bf16_t* __restrict__ op, int S) {
  int id = blockIdx.x;
  int bh = id & 31;
  int qt = 15 - (id >> 5);  // heavy-first dispatch order
  int tid = threadIdx.x;
  int w = tid >> 6, l = tid & 63;
  int ll = l & 15, lg = l >> 4;
  __shared__ char lds[49152];
  char* Pw = lds + 32768 + w * 4096;  // per-wave 32 x 64 bf16 P tile, swizzled

  int qbase = qt * 128;
  int qlo = qbase + w * 32;
  int qhi = qlo + 31;

  bf16x8 qf[2][2];
#pragma unroll
  for (int mi = 0; mi < 2; mi++) {
    const bf16_t* qrp = qb + ((size_t)bh * S + qbase + w * 32 + mi * 16 + ll) * 64;
#pragma unroll
    for (int kk = 0; kk < 2; kk++) qf[mi][kk] = *(const bf16x8*)(qrp + kk * 32 + lg * 8);
  }

  f32x4 Oacc[2][4];
  f32x4 z = {0.f, 0.f, 0.f, 0.f};
#pragma unroll
  for (int mi = 0; mi < 2; mi++)
#pragma unroll
    for (int i = 0; i < 4; i++) Oacc[mi][i] = z;
  float mrow[2], lrow[2];
#pragma unroll
  for (int mi = 0; mi < 2; mi++) { mrow[mi] = -INFINITY; lrow[mi] = 0.f; }

  int last = 2 * qt + 1;

  auto STAGE = [&](int kt, int c) {
    char* Kt = lds + c * 8192;
    char* Vt = lds + 16384 + c * 8192;
#pragma unroll
    for (int i = 0; i < 2; ++i) {
      int p = i * 4096 + tid * 16;
      int o = p ^ (((p >> 7) & 7) << 4);
      int r = o >> 7, cc = (o & 127) >> 1;
      gload_lds16(kb + ((size_t)bh * S + kt * 64 + r) * 64 + cc, Kt + p);
    }
#pragma unroll
    for (int i = 0; i < 2; ++i) {
      int p = i * 4096 + tid * 16;
      int o = p ^ (((p >> 7) & 7) << 4);
      int d = o >> 7, cc = (o & 127) >> 1;
      gload_lds16(vbT + ((size_t)bh * 64 + d) * S + kt * 64 + cc, Vt + p);
    }
  };

  STAGE(0, 0);
  int c = 0;
  for (int kt = 0; kt <= last; ++kt) {
    __builtin_amdgcn_s_barrier();
    if (kt < last) {
      STAGE(kt + 1, c ^ 1);
      asm volatile("s_waitcnt vmcnt(4)" ::: "memory");
    } else {
      asm volatile("s_waitcnt vmcnt(0)" ::: "memory");
    }
    __builtin_amdgcn_s_barrier();
    asm volatile("" ::: "memory");

    if (kt * 64 <= qhi) {
      char* Kt = lds + c * 8192;
      char* Vt = lds + 16384 + c * 8192;

      // --- S^T = K Q^T (A=K rows -> C rows = k; B=Q rows -> C cols = q) ---
      bf16x8 kf[4][2];
#pragma unroll
      for (int f = 0; f < 4; f++) {
        int row = f * 16 + ll;
#pragma unroll
        for (int kk = 0; kk < 2; kk++) {
          int o = (row << 7) + (kk << 6) + (lg << 4);
          kf[f][kk] = *(const bf16x8*)(Kt + (o ^ ((row & 7) << 4)));
        }
      }
      f32x4 sfr[2][4];
      __builtin_amdgcn_s_setprio(1);
#pragma unroll
      for (int mi = 0; mi < 2; mi++)
#pragma unroll
        for (int f = 0; f < 4; f++) {
          sfr[mi][f] = z;
#pragma unroll
          for (int kk = 0; kk < 2; kk++)
            sfr[mi][f] = __builtin_amdgcn_mfma_f32_16x16x32_bf16(
                kf[f][kk], qf[mi][kk], sfr[mi][f], 0, 0, 0);
        }
      __builtin_amdgcn_s_setprio(0);

      // --- mask + scale + in-lane max (lane owns q = mi*16+ll; k = f*16+lg*4+j) ---
      bool diag = (kt * 64 + 63) > qlo;
      float mx[2];
#pragma unroll
      for (int mi = 0; mi < 2; mi++) {
        int gq = qlo + mi * 16 + ll;
        float m_ = -INFINITY;
#pragma unroll
        for (int f = 0; f < 4; f++)
#pragma unroll
          for (int j = 0; j < 4; j++) {
            float s = sfr[mi][f][j] * 0.125f;
            if (diag && (kt * 64 + f * 16 + lg * 4 + j) > gq) s = -INFINITY;
            sfr[mi][f][j] = s;
            m_ = fmaxf(m_, s);
          }
        m_ = fmaxf(m_, __shfl_xor(m_, 16));
        m_ = fmaxf(m_, __shfl_xor(m_, 32));
        mx[mi] = m_;
      }

      // --- T13 defer-rescale: skip O-rescale when max growth <= 8 ---
      bool ok = (mx[0] <= mrow[0] + 8.f) && (mx[1] <= mrow[1] + 8.f);
      if (!__all(ok)) {
#pragma unroll
        for (int mi = 0; mi < 2; mi++) {
          float mnew = fmaxf(mrow[mi], mx[mi]);
          float fj = __expf(mrow[mi] - mnew);
          mrow[mi] = mnew;
          lrow[mi] *= fj;
#pragma unroll
          for (int j = 0; j < 4; j++) {
            float frow = __shfl(fj, (lg << 2) + j);  // fj lives at lane ll = q_row
#pragma unroll
            for (int fd = 0; fd < 4; fd++) Oacc[mi][fd][j] *= frow;
          }
        }
      }

      // --- exp, row-sum, packed P -> per-wave LDS ---
#pragma unroll
      for (int mi = 0; mi < 2; mi++) {
        float sum = 0.f;
        int q = mi * 16 + ll;
#pragma unroll
        for (int f = 0; f < 4; f++) {
          float p0 = __expf(sfr[mi][f][0] - mrow[mi]);
          float p1 = __expf(sfr[mi][f][1] - mrow[mi]);
          float p2 = __expf(sfr[mi][f][2] - mrow[mi]);
          float p3 = __expf(sfr[mi][f][3] - mrow[mi]);
          sum += (p0 + p1) + (p2 + p3);
          uint2 pk;
          pk.x = (unsigned)f2bf(p0) | ((unsigned)f2bf(p1) << 16);
          pk.y = (unsigned)f2bf(p2) | ((unsigned)f2bf(p3) << 16);
          int o = (q << 7) + ((f * 16 + lg * 4) << 1);
          *(uint2*)(Pw + (o ^ ((q & 7) << 4))) = pk;
        }
        sum += __shfl_xor(sum, 16);
        sum += __shfl_xor(sum, 32);
        lrow[mi] += sum;
      }

      // --- O += P V ---
      bf16x8 vf2[4][2];
#pragma unroll
      for (int fd = 0; fd < 4; fd++) {
        int row = fd * 16 + ll;
#pragma unroll
        for (int kk = 0; kk < 2; kk++) {
          int o = (row << 7) + (kk << 6) + (lg << 4);
          vf2[fd][kk] = *(const bf16x8*)(Vt + (o ^ ((row & 7) << 4)));
        }
      }
      bf16x8 pf[2][2];
#pragma unroll
      for (int mi = 0; mi < 2; mi++) {
        int pr = mi * 16 + ll;
#pragma unroll
        for (int kk = 0; kk < 2; kk++) {
          int o = (pr << 7) + (kk << 6) + (lg << 4);
          pf[mi][kk] = *(const bf16x8*)(Pw + (o ^ ((pr & 7) << 4)));
        }
      }
      __builtin_amdgcn_s_setprio(1);
#pragma unroll
      for (int mi = 0; mi < 2; mi++)
#pragma unroll
        for (int fd = 0; fd < 4; fd++)
#pragma unroll
          for (int kk = 0; kk < 2; kk++)
            Oacc[mi][fd] = __builtin_amdgcn_mfma_f32_16x16x32_bf16(
                pf[mi][kk], vf2[fd][kk], Oacc[mi][fd], 0, 0, 0);
      __builtin_amdgcn_s_setprio(0);
    }
    c ^= 1;
  }

  int b = bh >> 4, hh = bh & 15;
#pragma unroll
  for (int mi = 0; mi < 2; mi++) {
    float invA = 1.f / lrow[mi];
#pragma unroll
    for (int j = 0; j < 4; j++) {
      float inv = __shfl(invA, (lg << 2) + j);  // lrow lives at lane ll = q_row
      int srow = qbase + w * 32 + mi * 16 + lg * 4 + j;
#pragma unroll
      for (int fd = 0; fd < 4; fd++) {
        int col = (hh << 6) + (fd << 4) + ll;
        op[((size_t)b * S + srow) * 1024 + col] = __float2bfloat16(Oacc[mi][fd][j] * inv);
      }
    }
  }
}

// ---------------- launch ----------------
extern "C" void kernel_launch(void* const* d_in, const int* in_sizes, int n_in,
                              void* d_out, int out_size, void* d_ws, size_t ws_size,
                              hipStream_t stream) {
  const float* x = (const float*)d_in[0];
  const float* pos_emb = (const float*)d_in[1];
  const float* ln1_g = (const float*)d_in[2];
  const float* ln1_b = (const float*)d_in[3];
  const float* w_qkv = (const float*)d_in[4];
  const float* b_qkv = (const float*)d_in[5];
  const float* w_o = (const float*)d_in[6];
  const float* b_o = (const float*)d_in[7];
  const float* ln2_g = (const float*)d_in[8];
  const float* ln2_b = (const float*)d_in[9];
  const float* w_fc = (const float*)d_in[10];
  const float* b_fc = (const float*)d_in[11];
  const float* w_proj = (const float*)d_in[12];
  const float* b_proj = (const float*)d_in[13];

  char* ws = (char*)d_ws;
  auto take = [&](size_t bytes) {
    char* p = ws;
    ws += (bytes + 255) & ~(size_t)255;
    return p;
  };
  bf16_t* wqkvT = (bf16_t*)take(3072ull * 1024 * 2);
  bf16_t* woT = (bf16_t*)take(1024ull * 1024 * 2);
  bf16_t* wfcT = (bf16_t*)take(4096ull * 1024 * 2);
  bf16_t* wprojT = (bf16_t*)take(1024ull * 4096 * 2);
  bf16_t* h = (bf16_t*)take(4096ull * 1024 * 2);
  bf16_t* qbuf = (bf16_t*)take(32ull * 2048 * 64 * 2);
  bf16_t* kbuf = (bf16_t*)take(32ull * 2048 * 64 * 2);
  bf16_t* vbuf = (bf16_t*)take(32ull * 2048 * 64 * 2);
  bf16_t* aout = (bf16_t*)take(4096ull * 1024 * 2);
  float* x2 = (float*)take(4096ull * 1024 * 4);
  bf16_t* mb = (bf16_t*)take(4096ull * 1024 * 2);
  bf16_t* fca = (bf16_t*)qbuf;  // aliases dead q/k/v/aout buffers (32MB)

  dim3 tb(32, 8);
  wtrans_kernel<<<dim3(3072 / 32, 1024 / 32), tb, 0, stream>>>(w_qkv, wqkvT, 1024, 3072);
  wtrans_kernel<<<dim3(1024 / 32, 1024 / 32), tb, 0, stream>>>(w_o, woT, 1024, 1024);
  wtrans_kernel<<<dim3(4096 / 32, 1024 / 32), tb, 0, stream>>>(w_fc, wfcT, 1024, 4096);
  wtrans_kernel<<<dim3(1024 / 32, 4096 / 32), tb, 0, stream>>>(w_proj, wprojT, 4096, 1024);

  ln_kernel<<<4096, 256, 0, stream>>>(x, ln1_g, ln1_b, pos_emb, h, 2048);

  gemm_bt<0, 0><<<dim3(768), 256, 0, stream>>>(h, wqkvT, b_qkv, nullptr, nullptr,
                                               nullptr, qbuf, kbuf, vbuf, 4096, 3072, 1024);

  attn_kernel<<<dim3(512), 256, 0, stream>>>(qbuf, kbuf, vbuf, aout, 2048);

  gemm_bt<1, 1><<<dim3(256), 256, 0, stream>>>(aout, woT, b_o, x, x2, nullptr,
                                               nullptr, nullptr, nullptr, 4096, 1024, 1024);

  ln_kernel<<<4096, 256, 0, stream>>>(x2, ln2_g, ln2_b, nullptr, mb, 2048);

  gemm_bt<2, 0><<<dim3(1024), 256, 0, stream>>>(mb, wfcT, b_fc, nullptr, nullptr,
                                                fca, nullptr, nullptr, nullptr, 4096, 4096, 1024);

  gemm_bt<1, 1><<<dim3(256), 256, 0, stream>>>(fca, wprojT, b_proj, x2, (float*)d_out,
                                               nullptr, nullptr, nullptr, nullptr, 4096, 1024, 4096);
}